// Round 4
// baseline (211.162 us; speedup 1.0000x reference)
//
#include <hip/hip_runtime.h>
#include <hip/hip_bf16.h>

// ReBASED attention R4: 32x32x16 MFMA both GEMMs, P stays in registers.
// S^T = K·Q^T via mfma_32x32x16 (A=K-frag, B=Q-frag-in-registers). Its C-layout
// (qrow = lane&31, kcol = (reg&3)+8*(reg>>2)+4*(lane>>5)) is half of the PV
// A-frag per lane; the other half comes from lane^32 via 2 shfl_xor per k-step.
// Q fragments loaded global->registers (no Qs LDS). Uniform paired q-tiles,
// double-buffered K/V staging with register prefetch. grid=(8,64), 256 thr.

#define SEQ 2048
#define HD  64
#define BQ  128
#define BK  64
#define LK  72   // row stride in shorts (144 B): b128-aligned, 4-bank shift/row

typedef __attribute__((ext_vector_type(8)))  short bf16x8;
typedef __attribute__((ext_vector_type(16))) float f32x16;

__device__ inline unsigned packbf(float a, float b) {
    __hip_bfloat162 hh = __float22bfloat162_rn(make_float2(a, b));  // a->lo, b->hi
    union { __hip_bfloat162 h2; unsigned u; } cv; cv.h2 = hh; return cv.u;
}

__global__ __launch_bounds__(256, 2)
void rebased_r4_kernel(const float* __restrict__ qg,
                       const float* __restrict__ kg,
                       const float* __restrict__ vg,
                       float* __restrict__ og) {
    __shared__ __align__(16) unsigned short Ks[2][BK][LK];   // K[kcol][d] bf16
    __shared__ __align__(16) unsigned short Vs[2][HD][LK];   // V^T[d][kcol] bf16

    const int t    = threadIdx.x;
    const int lane = t & 63;
    const int w    = t >> 6;        // wave: q-rows [w*32, w*32+32)
    const int l5   = lane & 31;
    const int h    = lane >> 5;     // half-wave
    const int pj   = blockIdx.x;
    const int head = blockIdx.y;
    const size_t base = (size_t)head * SEQ * HD;
    const int d4g = t & 15, rp = t >> 4;

    #pragma unroll
    for (int seg = 0; seg < 2; ++seg) {
        const int qt = seg ? pj : (15 - pj);    // big tile first
        const int ktmax = 2 * qt + 1;
        const int qrow_min = qt * BQ + w * 32;
        const int qrow = qrow_min + l5;

        // ---- Q fragments -> registers (global fp32 -> bf16, scale folded) ----
        bf16x8 qf[4];
        {
            const float* qp = qg + base + (size_t)qrow * HD + 8 * h;
            #pragma unroll
            for (int ds = 0; ds < 4; ++ds) {
                float4 a = *(const float4*)(qp + ds * 16);
                float4 b = *(const float4*)(qp + ds * 16 + 4);
                union { unsigned u[4]; bf16x8 v; } cv;
                cv.u[0] = packbf(a.x * 0.125f, a.y * 0.125f);
                cv.u[1] = packbf(a.z * 0.125f, a.w * 0.125f);
                cv.u[2] = packbf(b.x * 0.125f, b.y * 0.125f);
                cv.u[3] = packbf(b.z * 0.125f, b.w * 0.125f);
                qf[ds] = cv.v;
            }
        }

        // ---- load kt=0 K/V into registers ----
        float4 kreg[4], vreg[4];
        {
            const float4* ksrc = (const float4*)(kg + base);
            const float4* vsrc = (const float4*)(vg + base);
            #pragma unroll
            for (int l = 0; l < 4; ++l) kreg[l] = ksrc[t + l * 256];
            #pragma unroll
            for (int p = 0; p < 2; ++p) {
                int r0 = p * 32 + rp * 2;
                vreg[2 * p]     = vsrc[r0 * 16 + d4g];
                vreg[2 * p + 1] = vsrc[(r0 + 1) * 16 + d4g];
            }
        }
        __syncthreads();   // prior segment's LDS reads complete

        // ---- write kt=0 into buffer 0 ----
        #pragma unroll
        for (int l = 0; l < 4; ++l) {
            int f = t + l * 256, row = f >> 4, d4 = (f & 15) << 2;
            unsigned* dst = (unsigned*)&Ks[0][row][d4];
            dst[0] = packbf(kreg[l].x, kreg[l].y);
            dst[1] = packbf(kreg[l].z, kreg[l].w);
        }
        #pragma unroll
        for (int p = 0; p < 2; ++p) {
            int r0 = p * 32 + rp * 2;
            float a0[4] = {vreg[2*p].x, vreg[2*p].y, vreg[2*p].z, vreg[2*p].w};
            float a1[4] = {vreg[2*p+1].x, vreg[2*p+1].y, vreg[2*p+1].z, vreg[2*p+1].w};
            #pragma unroll
            for (int j = 0; j < 4; ++j)
                *(unsigned*)&Vs[0][d4g * 4 + j][r0] = packbf(a0[j], a1[j]);
        }
        __syncthreads();

        f32x16 oa0, oa1;
        #pragma unroll
        for (int i = 0; i < 16; ++i) { oa0[i] = 0.f; oa1[i] = 0.f; }
        float zadd = 0.f;

        for (int kt = 0; kt <= ktmax; ++kt) {
            const int cur = kt & 1;

            // ---- prefetch kt+1 into registers ----
            if (kt < ktmax) {
                const float4* ksrc = (const float4*)(kg + base + (size_t)(kt + 1) * BK * HD);
                const float4* vsrc = (const float4*)(vg + base + (size_t)(kt + 1) * BK * HD);
                #pragma unroll
                for (int l = 0; l < 4; ++l) kreg[l] = ksrc[t + l * 256];
                #pragma unroll
                for (int p = 0; p < 2; ++p) {
                    int r0 = p * 32 + rp * 2;
                    vreg[2 * p]     = vsrc[r0 * 16 + d4g];
                    vreg[2 * p + 1] = vsrc[(r0 + 1) * 16 + d4g];
                }
            }

            if (kt * 64 <= qrow_min + 31) {   // wave has unmasked work
                // ---- S^T = K·Q^T : two 32-row K tiles, K-depth 64 in 4 steps ----
                f32x16 st0, st1;
                #pragma unroll
                for (int i = 0; i < 16; ++i) { st0[i] = 0.f; st1[i] = 0.f; }
                #pragma unroll
                for (int ds = 0; ds < 4; ++ds) {
                    bf16x8 k0 = *(const bf16x8*)&Ks[cur][l5][ds * 16 + 8 * h];
                    bf16x8 k1 = *(const bf16x8*)&Ks[cur][32 + l5][ds * 16 + 8 * h];
                    st0 = __builtin_amdgcn_mfma_f32_32x32x16_bf16(k0, qf[ds], st0, 0, 0, 0);
                    st1 = __builtin_amdgcn_mfma_f32_32x32x16_bf16(k1, qf[ds], st1, 0, 0, 0);
                }

                // ---- square + causal mask + z + pack to b32 kcol-pairs ----
                unsigned ppk[2][4][2];
                const bool needmask = (kt * 64 + 63 > qrow_min);
                const int kbase = kt * 64 + 4 * h;
                #pragma unroll
                for (int Mt = 0; Mt < 2; ++Mt) {
                    #pragma unroll
                    for (int r2 = 0; r2 < 4; ++r2) {
                        float p[4];
                        #pragma unroll
                        for (int e = 0; e < 4; ++e) {
                            float s = Mt ? st1[4 * r2 + e] : st0[4 * r2 + e];
                            float pv = s * s;
                            if (needmask && (kbase + 32 * Mt + 8 * r2 + e > qrow)) pv = 0.f;
                            p[e] = pv;
                        }
                        zadd += (p[0] + p[1]) + (p[2] + p[3]);
                        ppk[Mt][r2][0] = packbf(p[0], p[1]);
                        ppk[Mt][r2][1] = packbf(p[2], p[3]);
                    }
                }

                // ---- O += P·V : assemble PV A-frags (half own, half from lane^32) ----
                #pragma unroll
                for (int kst = 0; kst < 4; ++kst) {
                    const int b0 = 2 * kst, b1 = 2 * kst + 1;   // 8-kcol block ids
                    unsigned a0 = ppk[b0 >> 2][b0 & 3][0], a1 = ppk[b0 >> 2][b0 & 3][1];
                    unsigned c0 = ppk[b1 >> 2][b1 & 3][0], c1 = ppk[b1 >> 2][b1 & 3][1];
                    unsigned s0 = h ? a0 : c0, s1 = h ? a1 : c1;      // partner's block
                    unsigned g0 = (unsigned)__shfl_xor((int)s0, 32, 64);
                    unsigned g1 = (unsigned)__shfl_xor((int)s1, 32, 64);
                    union { unsigned u[4]; bf16x8 v; } pa;
                    pa.u[0] = h ? g0 : a0;   // k = 16*kst+8h + {0,1}
                    pa.u[1] = h ? g1 : a1;   //              + {2,3}
                    pa.u[2] = h ? c0 : g0;   //              + {4,5}
                    pa.u[3] = h ? c1 : g1;   //              + {6,7}
                    bf16x8 v0 = *(const bf16x8*)&Vs[cur][l5][kst * 16 + 8 * h];
                    bf16x8 v1 = *(const bf16x8*)&Vs[cur][32 + l5][kst * 16 + 8 * h];
                    oa0 = __builtin_amdgcn_mfma_f32_32x32x16_bf16(pa.v, v0, oa0, 0, 0, 0);
                    oa1 = __builtin_amdgcn_mfma_f32_32x32x16_bf16(pa.v, v1, oa1, 0, 0, 0);
                }
            }

            // ---- write prefetched kt+1 into the other buffer ----
            if (kt < ktmax) {
                const int nb = cur ^ 1;
                #pragma unroll
                for (int l = 0; l < 4; ++l) {
                    int f = t + l * 256, row = f >> 4, d4 = (f & 15) << 2;
                    unsigned* dst = (unsigned*)&Ks[nb][row][d4];
                    dst[0] = packbf(kreg[l].x, kreg[l].y);
                    dst[1] = packbf(kreg[l].z, kreg[l].w);
                }
                #pragma unroll
                for (int p = 0; p < 2; ++p) {
                    int r0 = p * 32 + rp * 2;
                    float a0[4] = {vreg[2*p].x, vreg[2*p].y, vreg[2*p].z, vreg[2*p].w};
                    float a1[4] = {vreg[2*p+1].x, vreg[2*p+1].y, vreg[2*p+1].z, vreg[2*p+1].w};
                    #pragma unroll
                    for (int j = 0; j < 4; ++j)
                        *(unsigned*)&Vs[nb][d4g * 4 + j][r0] = packbf(a0[j], a1[j]);
                }
            }
            __syncthreads();
        }

        // ---- epilogue: z finish + divide + store ----
        float zf = zadd + __shfl_xor(zadd, 32, 64);   // both halves: z[qrow w*32+l5]
        float zinv = 1.f / (zf + 1e-6f);
        float* odst = og + base + (size_t)(qt * BQ) * HD;
        #pragma unroll
        for (int r = 0; r < 16; ++r) {
            int rowi = (r & 3) + 8 * (r >> 2) + 4 * h;          // local q-row of reg r
            float inv = __shfl(zinv, rowi, 64);
            int rg = w * 32 + rowi;
            odst[(size_t)rg * HD + l5]      = oa0[r] * inv;
            odst[(size_t)rg * HD + 32 + l5] = oa1[r] * inv;
        }
    }
}

extern "C" void kernel_launch(void* const* d_in, const int* in_sizes, int n_in,
                              void* d_out, int out_size, void* d_ws, size_t ws_size,
                              hipStream_t stream) {
    const float* q = (const float*)d_in[0];
    const float* k = (const float*)d_in[1];
    const float* v = (const float*)d_in[2];
    float* out = (float*)d_out;

    dim3 grid(8, 64);    // 8 uniform q-tile pairs x 64 heads = 512 blocks = 2/CU
    dim3 block(256);
    rebased_r4_kernel<<<grid, block, 0, stream>>>(q, k, v, out);
}